// Round 6
// baseline (149.909 us; speedup 1.0000x reference)
//
#include <hip/hip_runtime.h>

#define NB 32
#define NT 512
#define ND 80
#define NK 16
#define NP 64

// D*log(2*pi)
#define C_DLOG2PI (80.0f * 1.837877066409345f)

#define REG_CHUNKS 16
#define APAD 88   // LDS row pitch in bf16 elems: 176B = 11*16B aligned, 2-way bank aliasing (free)

typedef __attribute__((ext_vector_type(8))) short bf16x8;
typedef __attribute__((ext_vector_type(4))) short s16x4;
typedef __attribute__((ext_vector_type(4))) float f32x4;

__device__ inline unsigned short f2bf(float f) {
    unsigned u = __float_as_uint(f);
    unsigned r = (u + 0x7fffu + ((u >> 16) & 1u)) >> 16;  // RNE
    return (unsigned short)r;
}

__global__ void zero_out_kernel(float* out) { out[0] = 0.0f; }

// ---------------------------------------------------------------------------
// Triangular inversion, straight-line by construction AND forced-inline.
// R5 lesson: `__device__ inline` template recursion was NOT inlined (VGPR=48,
// v[] on stack -> scratch in L2, 140us). always_inline flattens the whole
// 80-level chain into one body; then every v[] index is compile-time constant
// -> SROA keeps v[80] in VGPRs.
// ---------------------------------------------------------------------------
template<int I, int J>
__forceinline__ __device__ void inv_dot(const float* __restrict__ Lrow, const float (&v)[ND],
                                        float& a0, float& a1, float& a2, float& a3) {
    if constexpr (J + 0 < I) a0 -= Lrow[J + 0] * v[J + 0];
    if constexpr (J + 1 < I) a1 -= Lrow[J + 1] * v[J + 1];
    if constexpr (J + 2 < I) a2 -= Lrow[J + 2] * v[J + 2];
    if constexpr (J + 3 < I) a3 -= Lrow[J + 3] * v[J + 3];
    if constexpr (J + 4 < I) inv_dot<I, J + 4>(Lrow, v, a0, a1, a2, a3);
}

template<int I>
__forceinline__ __device__ void inv_all(const float* __restrict__ Lg, float (&v)[ND],
                                        const int c, float& logdet) {
    if constexpr (I < ND) {
        const float* __restrict__ Lrow = Lg + I * ND;
        float a0 = (I == c) ? 1.0f : 0.0f;
        float a1 = 0.0f, a2 = 0.0f, a3 = 0.0f;
        if constexpr (I > 0) inv_dot<I, 0>(Lrow, v, a0, a1, a2, a3);
        const float d = Lrow[I];
        v[I] = ((a0 + a1) + (a2 + a3)) / d;
        logdet += logf(d);
        inv_all<I + 1>(Lg, v, c, logdet);
    }
}

// Per (b,k): invert the 80x80 lower-triangular L[sids[b]][k] in fp32,
// store Linv row-major as bf16 into ws, plus logdet (2*sum log diag).
// Thread c computes column c of Linv; all L reads are wave-uniform.
__global__ __launch_bounds__(128, 1) void inv_kernel(
    const float* __restrict__ L_subj,
    const int* __restrict__ sids,
    unsigned short* __restrict__ linv_ws,   // [NB*NK][ND*ND] bf16
    float* __restrict__ logdet_ws)          // [NB*NK]
{
    const int bk = blockIdx.x;
    const int b  = bk >> 4;
    const int k  = bk & 15;
    const int c  = threadIdx.x;   // column (valid c < ND)
    const int s  = __builtin_amdgcn_readfirstlane(sids[b]);
    const float* __restrict__ Lg = L_subj + (((size_t)s * NK + k) * ND * ND);

    __shared__ unsigned short T_sh[ND * APAD];

    float v[ND];
    float logdet = 0.0f;
    inv_all<0>(Lg, v, c, logdet);

    if (c < ND) {
        #pragma unroll
        for (int i = 0; i < ND; ++i) T_sh[i * APAD + c] = f2bf(v[i]);
    }
    if (c == 0) logdet_ws[bk] = 2.0f * logdet;
    __syncthreads();

    // coalesced bf16 write-out: 80 rows * 80 bf16 = 800 uint4
    uint4* dst = (uint4*)(linv_ws + (size_t)bk * (ND * ND));
    for (int i = threadIdx.x; i < ND * ND / 8; i += 128) {
        int n  = i / 10;
        int c8 = (i % 10) * 8;
        dst[i] = *(const uint4*)&T_sh[n * APAD + c8];
    }
}

// ---------------------------------------------------------------------------
// Block = (b, ttile of 128, k). Y = R(128x80) * Linv^T  via mfma 16x16x32 bf16
// (K padded to 96; last K-step lane-zeroed). mahal_t = sum_n Y[t][n]^2 via
// per-reg squares + butterfly-xor over lane bits 0..3. Then gamma-weighted
// accumulation of (C + logdet + mahal).
// ---------------------------------------------------------------------------
__global__ __launch_bounds__(256) void gemm_kernel(
    const float* __restrict__ x,
    const float* __restrict__ mu_subj,
    const float* __restrict__ gamma,
    const int* __restrict__ sids,
    const unsigned short* __restrict__ linv_ws,
    const float* __restrict__ logdet_ws,
    float* __restrict__ out)
{
    const int bx = blockIdx.x;          // 2048 = 32 b * 4 ttile * 16 k
    const int k  = bx & 15;
    const int tt = (bx >> 4) & 3;
    const int b  = bx >> 6;
    const int bk = b * NK + k;
    const int t0 = tt * 128;
    const int tid  = threadIdx.x;
    const int lane = tid & 63;
    const int wv   = tid >> 6;
    const int m    = lane & 15;
    const int g    = lane >> 4;
    const int s    = __builtin_amdgcn_readfirstlane(sids[b]);

    __shared__ unsigned short A_sh[128 * APAD];  // R tile, bf16
    __shared__ unsigned short B_sh[ND * APAD];   // Linv rows, bf16

    // --- stage A: R[r][j] = bf16(x[b][t0+r][j] - mu[s][k][j]), 2 thr/row ---
    {
        const int r = tid >> 1;
        const int h = tid & 1;
        const float4* xp = (const float4*)(x + ((size_t)(b * NT + t0 + r)) * ND + h * 40);
        const float4* mp = (const float4*)(mu_subj + ((size_t)(s * NK + k)) * ND + h * 40);
        #pragma unroll
        for (int q = 0; q < 10; ++q) {
            float4 xv = xp[q];
            float4 mv = mp[q];
            s16x4 pk;
            pk.x = (short)f2bf(xv.x - mv.x);
            pk.y = (short)f2bf(xv.y - mv.y);
            pk.z = (short)f2bf(xv.z - mv.z);
            pk.w = (short)f2bf(xv.w - mv.w);
            *(s16x4*)&A_sh[r * APAD + h * 40 + q * 4] = pk;
        }
    }
    // --- stage B: Linv bf16 rows (row n holds Linv[n][0..79]) ---
    {
        const uint4* src = (const uint4*)(linv_ws + (size_t)bk * (ND * ND));
        for (int i = tid; i < ND * ND / 8; i += 256) {
            int n  = i / 10;
            int c8 = (i % 10) * 8;
            *(uint4*)&B_sh[n * APAD + c8] = src[i];
        }
    }
    __syncthreads();

    // --- MFMA: per wave, 32 t-rows x 80 cols, K = 96 (3 steps of 32) ---
    f32x4 acc[2][5];
    #pragma unroll
    for (int mt = 0; mt < 2; ++mt)
        #pragma unroll
        for (int nt = 0; nt < 5; ++nt)
            acc[mt][nt] = (f32x4){0.f, 0.f, 0.f, 0.f};

    const bf16x8 zf = {0, 0, 0, 0, 0, 0, 0, 0};
    #pragma unroll
    for (int ks = 0; ks < 3; ++ks) {
        const int kbase = ks * 32 + g * 8;
        bf16x8 af[2], bfr[5];
        if (kbase < ND) {
            af[0] = *(const bf16x8*)&A_sh[(wv * 32 + m) * APAD + kbase];
            af[1] = *(const bf16x8*)&A_sh[(wv * 32 + 16 + m) * APAD + kbase];
            #pragma unroll
            for (int nt = 0; nt < 5; ++nt)
                bfr[nt] = *(const bf16x8*)&B_sh[(nt * 16 + m) * APAD + kbase];
        } else {
            af[0] = zf; af[1] = zf;
            #pragma unroll
            for (int nt = 0; nt < 5; ++nt) bfr[nt] = zf;
        }
        #pragma unroll
        for (int mt = 0; mt < 2; ++mt)
            #pragma unroll
            for (int nt = 0; nt < 5; ++nt)
                acc[mt][nt] = __builtin_amdgcn_mfma_f32_16x16x32_bf16(
                    af[mt], bfr[nt], acc[mt][nt], 0, 0, 0);
    }

    // --- epilogue: mahal per t, gamma weighting ---
    const float ldet_c = logdet_ws[bk] + C_DLOG2PI;
    float local = 0.0f;
    #pragma unroll
    for (int mt = 0; mt < 2; ++mt) {
        float p0 = 0.f, p1 = 0.f, p2 = 0.f, p3 = 0.f;
        #pragma unroll
        for (int nt = 0; nt < 5; ++nt) {
            p0 += acc[mt][nt][0] * acc[mt][nt][0];
            p1 += acc[mt][nt][1] * acc[mt][nt][1];
            p2 += acc[mt][nt][2] * acc[mt][nt][2];
            p3 += acc[mt][nt][3] * acc[mt][nt][3];
        }
        #pragma unroll
        for (int mask = 1; mask < 16; mask <<= 1) {
            p0 += __shfl_xor(p0, mask);
            p1 += __shfl_xor(p1, mask);
            p2 += __shfl_xor(p2, mask);
            p3 += __shfl_xor(p3, mask);
        }
        if (m < 4) {
            float mm = (m == 0) ? p0 : (m == 1) ? p1 : (m == 2) ? p2 : p3;
            int t = t0 + wv * 32 + mt * 16 + g * 4 + m;
            float gam = gamma[((size_t)(b * NT + t)) * NK + k];
            local += gam * (mm + ldet_c);
        }
    }

    // block reduce + atomic
    __shared__ float partial[4];
    #pragma unroll
    for (int off = 32; off > 0; off >>= 1) local += __shfl_down(local, off);
    if (lane == 0) partial[wv] = local;
    __syncthreads();
    if (tid == 0) {
        float sum = partial[0] + partial[1] + partial[2] + partial[3];
        atomicAdd(out, sum * (0.5f / (NB * NT)));
    }
}

// ---------------------------------------------------------------------------
// Regularization: grid (chunk, subject).
// ---------------------------------------------------------------------------
__global__ __launch_bounds__(256) void reg_kernel(
    const float* __restrict__ mu_pop,
    const float* __restrict__ L_pop,
    const float* __restrict__ mu_subj,
    const float* __restrict__ L_subj,
    const int* __restrict__ sids,
    float* __restrict__ out)
{
    const int p   = blockIdx.y;
    const int c   = blockIdx.x;
    const int tid = threadIdx.x;

    __shared__ float scale_sh;
    __shared__ int   present_sh;
    __shared__ float partial[4];

    if (tid == 0) {
        unsigned long long seen = 0ull;
        int present = 0;
        for (int b = 0; b < NB; ++b) {
            int sb = sids[b];
            seen |= (1ull << sb);
            present |= (sb == p) ? 1 : 0;
        }
        present_sh = present;
        scale_sh = (float)__popcll(seen) * (1.0f / (float)NP);
    }
    __syncthreads();
    if (!present_sh) return;  // uniform exit

    float acc = 0.0f;
    {
        const float4* Ls4 = reinterpret_cast<const float4*>(L_subj + (size_t)p * NK * ND * ND);
        const float4* Lp4 = reinterpret_cast<const float4*>(L_pop);
        const int n4 = NK * ND * ND / 4;
        for (int i = c * 256 + tid; i < n4; i += REG_CHUNKS * 256) {
            float4 a = Ls4[i];
            float4 bq = Lp4[i];
            float dx = a.x - bq.x, dy = a.y - bq.y, dz = a.z - bq.z, dw = a.w - bq.w;
            acc += dx * dx + dy * dy + dz * dz + dw * dw;
        }
    }
    if (c == 0) {
        const float4* ms4 = reinterpret_cast<const float4*>(mu_subj + (size_t)p * NK * ND);
        const float4* mp4 = reinterpret_cast<const float4*>(mu_pop);
        const int n4 = NK * ND / 4;
        for (int i = tid; i < n4; i += 256) {
            float4 a = ms4[i];
            float4 bq = mp4[i];
            float dx = a.x - bq.x, dy = a.y - bq.y, dz = a.z - bq.z, dw = a.w - bq.w;
            acc += dx * dx + dy * dy + dz * dz + dw * dw;
        }
    }

    #pragma unroll
    for (int off = 32; off > 0; off >>= 1) acc += __shfl_down(acc, off);
    int wave = tid >> 6;
    if ((tid & 63) == 0) partial[wave] = acc;
    __syncthreads();
    if (tid == 0) {
        float total = partial[0] + partial[1] + partial[2] + partial[3];
        atomicAdd(out, scale_sh * 0.05f * total);  // lambda/2 = 0.05 both terms
    }
}

extern "C" void kernel_launch(void* const* d_in, const int* in_sizes, int n_in,
                              void* d_out, int out_size, void* d_ws, size_t ws_size,
                              hipStream_t stream) {
    (void)in_sizes; (void)n_in; (void)ws_size; (void)out_size;
    const float* x       = (const float*)d_in[0];
    const float* mu_pop  = (const float*)d_in[1];
    const float* L_pop   = (const float*)d_in[2];
    const float* mu_subj = (const float*)d_in[3];
    const float* L_subj  = (const float*)d_in[4];
    const float* gamma   = (const float*)d_in[5];
    const int*   sids    = (const int*)d_in[6];
    float* out = (float*)d_out;

    unsigned short* linv_ws = (unsigned short*)d_ws;                       // 6.55 MB
    float* logdet_ws = (float*)((char*)d_ws + (size_t)NB * NK * ND * ND * 2);

    hipLaunchKernelGGL(zero_out_kernel, dim3(1), dim3(1), 0, stream, out);
    hipLaunchKernelGGL(inv_kernel, dim3(NB * NK), dim3(128), 0, stream,
                       L_subj, sids, linv_ws, logdet_ws);
    hipLaunchKernelGGL(gemm_kernel, dim3(NB * 4 * NK), dim3(256), 0, stream,
                       x, mu_subj, gamma, sids, linv_ws, logdet_ws, out);
    hipLaunchKernelGGL(reg_kernel, dim3(REG_CHUNKS, NP), dim3(256), 0, stream,
                       mu_pop, L_pop, mu_subj, L_subj, sids, out);
}

// Round 7
// 114.191 us; speedup vs baseline: 1.3128x; 1.3128x over previous
//
#include <hip/hip_runtime.h>

#define NB 32
#define NT 512
#define ND 80
#define NK 16
#define NP 64

// D*log(2*pi)
#define C_DLOG2PI (80.0f * 1.837877066409345f)

#define REG_CHUNKS 16
#define APAD 88    // T_sh pitch in bf16 elems (16B-aligned rows, 2-way bank aliasing = free)
#define VPITCH 84  // V_sh pitch in fp32 elems: 336B, %16==0 so float4 reloads stay aligned

typedef __attribute__((ext_vector_type(8))) short bf16x8;
typedef __attribute__((ext_vector_type(4))) short s16x4;
typedef __attribute__((ext_vector_type(4))) float f32x4;

__device__ inline unsigned short f2bf(float f) {
    unsigned u = __float_as_uint(f);
    unsigned r = (u + 0x7fffu + ((u >> 16) & 1u)) >> 16;  // RNE
    return (unsigned short)r;
}

__global__ void zero_out_kernel(float* out) { out[0] = 0.0f; }

// ---------------------------------------------------------------------------
// Triangular inversion, chunked so NO per-thread 80-array exists.
// R3-R6 lesson: any formulation with a private float v[80] ends up as an
// alloca in scratch (VGPR=48, 3160 scratch loads/thread at ~200cyc -> 150us)
// regardless of unroll pragmas / if-constexpr / always_inline. Fix: process
// rows in chunks of 16. Live state is vseg[16]/acc[16]/vj[16], all statically
// indexed under small unrolls (guaranteed VGPRs). Completed v-values are
// parked in LDS V_sh[c][i] and reloaded 16-at-a-time as float4s.
// All threads work on the SAME row concurrently, so every L read is
// wave-uniform -> merged s_load_dwordx4/x8 from global.
// ---------------------------------------------------------------------------
__global__ __launch_bounds__(128, 1) void inv_kernel(
    const float* __restrict__ L_subj,
    const int* __restrict__ sids,
    unsigned short* __restrict__ linv_ws,   // [NB*NK][ND*ND] bf16
    float* __restrict__ logdet_ws)          // [NB*NK]
{
    const int bk = blockIdx.x;
    const int b  = bk >> 4;
    const int k  = bk & 15;
    const int c  = threadIdx.x;   // column (valid c < ND; c>=ND compute garbage, never stored)
    const int s  = __builtin_amdgcn_readfirstlane(sids[b]);
    const float* __restrict__ Lg = L_subj + (((size_t)s * NK + k) * ND * ND);

    __shared__ __align__(16) float V_sh[128 * VPITCH];      // v history per column
    __shared__ __align__(16) unsigned short T_sh[ND * APAD]; // bf16 Linv, [i][c] for coalesced out

    float logdet = 0.0f;

    for (int base = 0; base < ND; base += 16) {
        float acc[16];
        #pragma unroll
        for (int r = 0; r < 16; ++r) acc[r] = ((base + r) == c) ? 1.0f : 0.0f;

        // part 1: dot with previous chunks' v (reloaded 16-wide from LDS)
        for (int jt = 0; jt < base; jt += 16) {
            float vj[16];
            #pragma unroll
            for (int q4 = 0; q4 < 4; ++q4)
                *(float4*)&vj[q4 * 4] = *(const float4*)&V_sh[c * VPITCH + jt + q4 * 4];
            #pragma unroll
            for (int r = 0; r < 16; ++r) {
                const float* __restrict__ Lrow = Lg + (base + r) * ND + jt;
                float a0 = 0.f, a1 = 0.f;
                #pragma unroll
                for (int q = 0; q < 16; q += 2) {
                    a0 += Lrow[q + 0] * vj[q + 0];
                    a1 += Lrow[q + 1] * vj[q + 1];
                }
                acc[r] -= a0 + a1;
            }
        }

        // part 2: within-chunk triangular recurrence (vseg register-resident)
        float vseg[16];
        #pragma unroll
        for (int r = 0; r < 16; ++r) {
            const int I = base + r;
            const float* __restrict__ Lrow = Lg + I * ND;
            float a = acc[r];
            #pragma unroll
            for (int q = 0; q < 16; ++q)
                if (q < r) a -= Lrow[base + q] * vseg[q];   // q,r static -> folds
            const float d = Lrow[I];
            const float val = a / d;
            vseg[r] = val;
            logdet += logf(d);
            V_sh[c * VPITCH + I] = val;
            if (c < ND) T_sh[I * APAD + c] = f2bf(val);
        }
    }

    if (c == 0) logdet_ws[bk] = 2.0f * logdet;
    __syncthreads();

    // coalesced bf16 write-out: 80 rows * 80 bf16 = 800 uint4
    uint4* dst = (uint4*)(linv_ws + (size_t)bk * (ND * ND));
    for (int i = threadIdx.x; i < ND * ND / 8; i += 128) {
        int n  = i / 10;
        int c8 = (i % 10) * 8;
        dst[i] = *(const uint4*)&T_sh[n * APAD + c8];
    }
}

// ---------------------------------------------------------------------------
// Block = (b, ttile of 128, k). Y = R(128x80) * Linv^T  via mfma 16x16x32 bf16
// (K padded to 96; last K-step lane-zeroed). mahal_t = sum_n Y[t][n]^2 via
// per-reg squares + butterfly-xor over lane bits 0..3. Then gamma-weighted
// accumulation of (C + logdet + mahal).
// ---------------------------------------------------------------------------
__global__ __launch_bounds__(256) void gemm_kernel(
    const float* __restrict__ x,
    const float* __restrict__ mu_subj,
    const float* __restrict__ gamma,
    const int* __restrict__ sids,
    const unsigned short* __restrict__ linv_ws,
    const float* __restrict__ logdet_ws,
    float* __restrict__ out)
{
    const int bx = blockIdx.x;          // 2048 = 32 b * 4 ttile * 16 k
    const int k  = bx & 15;
    const int tt = (bx >> 4) & 3;
    const int b  = bx >> 6;
    const int bk = b * NK + k;
    const int t0 = tt * 128;
    const int tid  = threadIdx.x;
    const int lane = tid & 63;
    const int wv   = tid >> 6;
    const int m    = lane & 15;
    const int g    = lane >> 4;
    const int s    = __builtin_amdgcn_readfirstlane(sids[b]);

    __shared__ unsigned short A_sh[128 * APAD];  // R tile, bf16
    __shared__ unsigned short B_sh[ND * APAD];   // Linv rows, bf16

    // --- stage A: R[r][j] = bf16(x[b][t0+r][j] - mu[s][k][j]), 2 thr/row ---
    {
        const int r = tid >> 1;
        const int h = tid & 1;
        const float4* xp = (const float4*)(x + ((size_t)(b * NT + t0 + r)) * ND + h * 40);
        const float4* mp = (const float4*)(mu_subj + ((size_t)(s * NK + k)) * ND + h * 40);
        #pragma unroll
        for (int q = 0; q < 10; ++q) {
            float4 xv = xp[q];
            float4 mv = mp[q];
            s16x4 pk;
            pk.x = (short)f2bf(xv.x - mv.x);
            pk.y = (short)f2bf(xv.y - mv.y);
            pk.z = (short)f2bf(xv.z - mv.z);
            pk.w = (short)f2bf(xv.w - mv.w);
            *(s16x4*)&A_sh[r * APAD + h * 40 + q * 4] = pk;
        }
    }
    // --- stage B: Linv bf16 rows (row n holds Linv[n][0..79]) ---
    {
        const uint4* src = (const uint4*)(linv_ws + (size_t)bk * (ND * ND));
        for (int i = tid; i < ND * ND / 8; i += 256) {
            int n  = i / 10;
            int c8 = (i % 10) * 8;
            *(uint4*)&B_sh[n * APAD + c8] = src[i];
        }
    }
    __syncthreads();

    // --- MFMA: per wave, 32 t-rows x 80 cols, K = 96 (3 steps of 32) ---
    f32x4 acc[2][5];
    #pragma unroll
    for (int mt = 0; mt < 2; ++mt)
        #pragma unroll
        for (int nt = 0; nt < 5; ++nt)
            acc[mt][nt] = (f32x4){0.f, 0.f, 0.f, 0.f};

    const bf16x8 zf = {0, 0, 0, 0, 0, 0, 0, 0};
    #pragma unroll
    for (int ks = 0; ks < 3; ++ks) {
        const int kbase = ks * 32 + g * 8;
        bf16x8 af[2], bfr[5];
        if (kbase < ND) {
            af[0] = *(const bf16x8*)&A_sh[(wv * 32 + m) * APAD + kbase];
            af[1] = *(const bf16x8*)&A_sh[(wv * 32 + 16 + m) * APAD + kbase];
            #pragma unroll
            for (int nt = 0; nt < 5; ++nt)
                bfr[nt] = *(const bf16x8*)&B_sh[(nt * 16 + m) * APAD + kbase];
        } else {
            af[0] = zf; af[1] = zf;
            #pragma unroll
            for (int nt = 0; nt < 5; ++nt) bfr[nt] = zf;
        }
        #pragma unroll
        for (int mt = 0; mt < 2; ++mt)
            #pragma unroll
            for (int nt = 0; nt < 5; ++nt)
                acc[mt][nt] = __builtin_amdgcn_mfma_f32_16x16x32_bf16(
                    af[mt], bfr[nt], acc[mt][nt], 0, 0, 0);
    }

    // --- epilogue: mahal per t, gamma weighting ---
    const float ldet_c = logdet_ws[bk] + C_DLOG2PI;
    float local = 0.0f;
    #pragma unroll
    for (int mt = 0; mt < 2; ++mt) {
        float p0 = 0.f, p1 = 0.f, p2 = 0.f, p3 = 0.f;
        #pragma unroll
        for (int nt = 0; nt < 5; ++nt) {
            p0 += acc[mt][nt][0] * acc[mt][nt][0];
            p1 += acc[mt][nt][1] * acc[mt][nt][1];
            p2 += acc[mt][nt][2] * acc[mt][nt][2];
            p3 += acc[mt][nt][3] * acc[mt][nt][3];
        }
        #pragma unroll
        for (int mask = 1; mask < 16; mask <<= 1) {
            p0 += __shfl_xor(p0, mask);
            p1 += __shfl_xor(p1, mask);
            p2 += __shfl_xor(p2, mask);
            p3 += __shfl_xor(p3, mask);
        }
        if (m < 4) {
            float mm = (m == 0) ? p0 : (m == 1) ? p1 : (m == 2) ? p2 : p3;
            int t = t0 + wv * 32 + mt * 16 + g * 4 + m;
            float gam = gamma[((size_t)(b * NT + t)) * NK + k];
            local += gam * (mm + ldet_c);
        }
    }

    // block reduce + atomic
    __shared__ float partial[4];
    #pragma unroll
    for (int off = 32; off > 0; off >>= 1) local += __shfl_down(local, off);
    if (lane == 0) partial[wv] = local;
    __syncthreads();
    if (tid == 0) {
        float sum = partial[0] + partial[1] + partial[2] + partial[3];
        atomicAdd(out, sum * (0.5f / (NB * NT)));
    }
}

// ---------------------------------------------------------------------------
// Regularization: grid (chunk, subject).
// ---------------------------------------------------------------------------
__global__ __launch_bounds__(256) void reg_kernel(
    const float* __restrict__ mu_pop,
    const float* __restrict__ L_pop,
    const float* __restrict__ mu_subj,
    const float* __restrict__ L_subj,
    const int* __restrict__ sids,
    float* __restrict__ out)
{
    const int p   = blockIdx.y;
    const int c   = blockIdx.x;
    const int tid = threadIdx.x;

    __shared__ float scale_sh;
    __shared__ int   present_sh;
    __shared__ float partial[4];

    if (tid == 0) {
        unsigned long long seen = 0ull;
        int present = 0;
        for (int b = 0; b < NB; ++b) {
            int sb = sids[b];
            seen |= (1ull << sb);
            present |= (sb == p) ? 1 : 0;
        }
        present_sh = present;
        scale_sh = (float)__popcll(seen) * (1.0f / (float)NP);
    }
    __syncthreads();
    if (!present_sh) return;  // uniform exit

    float acc = 0.0f;
    {
        const float4* Ls4 = reinterpret_cast<const float4*>(L_subj + (size_t)p * NK * ND * ND);
        const float4* Lp4 = reinterpret_cast<const float4*>(L_pop);
        const int n4 = NK * ND * ND / 4;
        for (int i = c * 256 + tid; i < n4; i += REG_CHUNKS * 256) {
            float4 a = Ls4[i];
            float4 bq = Lp4[i];
            float dx = a.x - bq.x, dy = a.y - bq.y, dz = a.z - bq.z, dw = a.w - bq.w;
            acc += dx * dx + dy * dy + dz * dz + dw * dw;
        }
    }
    if (c == 0) {
        const float4* ms4 = reinterpret_cast<const float4*>(mu_subj + (size_t)p * NK * ND);
        const float4* mp4 = reinterpret_cast<const float4*>(mu_pop);
        const int n4 = NK * ND / 4;
        for (int i = tid; i < n4; i += 256) {
            float4 a = ms4[i];
            float4 bq = mp4[i];
            float dx = a.x - bq.x, dy = a.y - bq.y, dz = a.z - bq.z, dw = a.w - bq.w;
            acc += dx * dx + dy * dy + dz * dz + dw * dw;
        }
    }

    #pragma unroll
    for (int off = 32; off > 0; off >>= 1) acc += __shfl_down(acc, off);
    int wave = tid >> 6;
    if ((tid & 63) == 0) partial[wave] = acc;
    __syncthreads();
    if (tid == 0) {
        float total = partial[0] + partial[1] + partial[2] + partial[3];
        atomicAdd(out, scale_sh * 0.05f * total);  // lambda/2 = 0.05 both terms
    }
}

extern "C" void kernel_launch(void* const* d_in, const int* in_sizes, int n_in,
                              void* d_out, int out_size, void* d_ws, size_t ws_size,
                              hipStream_t stream) {
    (void)in_sizes; (void)n_in; (void)ws_size; (void)out_size;
    const float* x       = (const float*)d_in[0];
    const float* mu_pop  = (const float*)d_in[1];
    const float* L_pop   = (const float*)d_in[2];
    const float* mu_subj = (const float*)d_in[3];
    const float* L_subj  = (const float*)d_in[4];
    const float* gamma   = (const float*)d_in[5];
    const int*   sids    = (const int*)d_in[6];
    float* out = (float*)d_out;

    unsigned short* linv_ws = (unsigned short*)d_ws;                       // 6.55 MB
    float* logdet_ws = (float*)((char*)d_ws + (size_t)NB * NK * ND * ND * 2);

    hipLaunchKernelGGL(zero_out_kernel, dim3(1), dim3(1), 0, stream, out);
    hipLaunchKernelGGL(inv_kernel, dim3(NB * NK), dim3(128), 0, stream,
                       L_subj, sids, linv_ws, logdet_ws);
    hipLaunchKernelGGL(gemm_kernel, dim3(NB * 4 * NK), dim3(256), 0, stream,
                       x, mu_subj, gamma, sids, linv_ws, logdet_ws, out);
    hipLaunchKernelGGL(reg_kernel, dim3(REG_CHUNKS, NP), dim3(256), 0, stream,
                       mu_pop, L_pop, mu_subj, L_subj, sids, out);
}